// Round 1
// baseline (1467.046 us; speedup 1.0000x reference)
//
#include <hip/hip_runtime.h>
#include <hip/hip_bf16.h>
#include <math.h>

// NeuralCDE fused kernel: 256 blocks x 256 threads; each block owns 16 batch
// rows for the full 256-step RK4 integration. Weights in VGPRs (bf16 frags),
// activations ping-pong in LDS (bf16), z/k/acc fp32 in registers.

typedef short bf16x8 __attribute__((ext_vector_type(8)));
typedef float f32x4  __attribute__((ext_vector_type(4)));

#define MFMA16(a, b, c) __builtin_amdgcn_mfma_f32_16x16x32_bf16((a), (b), (c), 0, 0, 0)

__device__ __forceinline__ unsigned short f2bf(float x) {
  unsigned int u = __float_as_uint(x);
  u += 0x7FFFu + ((u >> 16) & 1u);   // round-to-nearest-even
  return (unsigned short)(u >> 16);
}

// raw barrier: LDS-drain only (keeps global prefetch loads in flight).
__device__ __forceinline__ void barrier_lgkm() {
  asm volatile("s_waitcnt lgkmcnt(0)" ::: "memory");
  __builtin_amdgcn_s_barrier();
  asm volatile("" ::: "memory");
}

__global__ __launch_bounds__(256, 1) void cde_fused(
    const float* __restrict__ z0, const float* __restrict__ coeffs,
    const float* __restrict__ W1, const float* __restrict__ b1,
    const float* __restrict__ W2, const float* __restrict__ b2,
    const float* __restrict__ W3, const float* __restrict__ b3,
    const float* __restrict__ Wr, const float* __restrict__ br,
    float* __restrict__ out) {
  __shared__ __align__(16) unsigned short zbuf[2][16][136];  // bf16 activations, ping-pong (+8 pad)
  __shared__ __align__(16) float cbuf[2][16 * 128 * 4];      // piece coeffs, double buffer (2x32KB)

  const int tid  = (int)threadIdx.x;
  const int lane = tid & 63;
  const int wv   = tid >> 6;   // wave 0..3
  const int l15  = lane & 15;
  const int q    = lane >> 4;  // 0..3
  const int n0   = wv * 32;    // this wave's output-channel base
  const int row0 = (int)blockIdx.x * 16;

  // ---------------- weight fragments (one-time) ----------------
  // B-frag for 16x16x32: B[k][n], n = lane&15, k = (lane>>4)*8 + i
  bf16x8 wf1[2][4], wf2[2][4], wf3[2][4];
  float  bs1[2], bs2[2], bs3[2];
#pragma unroll
  for (int t = 0; t < 2; ++t) {
    const int n = n0 + 16 * t + l15;
    bs1[t] = b1[n]; bs2[t] = b2[n]; bs3[t] = b3[n];
#pragma unroll
    for (int ks = 0; ks < 4; ++ks) {
      bf16x8 fa, fb, fc;
#pragma unroll
      for (int i = 0; i < 8; ++i) {
        const int k = ks * 32 + q * 8 + i;
        fa[i] = (short)f2bf(W1[k * 128 + n]);
        fb[i] = (short)f2bf(W2[k * 128 + n]);
        fc[i] = (short)f2bf(W3[k * 128 + n]);
      }
      wf1[t][ks] = fa; wf2[t][ks] = fb; wf3[t][ks] = fc;
    }
  }

  // ---------------- coeff staging (reg prefetch -> LDS) ----------------
  f32x4 cfetch[8];
  auto coeff_load = [&](int p) {  // issue global loads for piece p into regs
#pragma unroll
    for (int i = 0; i < 8; ++i) {
      const int f = i * 256 + tid;           // 0..2047 = row*128 + ch
      const int row = f >> 7, ch = f & 127;
      cfetch[i] = *(const f32x4*)(coeffs + ((size_t)((row0 + row) * 64 + p) * 128 + ch) * 4);
    }
  };
  auto coeff_store = [&](int p) {  // write staged regs into cbuf[p&1]
    const int b = p & 1;
#pragma unroll
    for (int i = 0; i < 8; ++i) {
      const int f = i * 256 + tid;
      *(f32x4*)&cbuf[b][(size_t)f * 4] = cfetch[i];
    }
  };

  // ---------------- prologue: z0 + piece-0 coeffs ----------------
  float zr[8];  // fp32 state, D-frag layout: e = t*4+r -> (row 4q+r, ch n0+16t+l15)
#pragma unroll
  for (int t = 0; t < 2; ++t)
#pragma unroll
    for (int r = 0; r < 4; ++r)
      zr[t * 4 + r] = z0[(size_t)(row0 + q * 4 + r) * 128 + n0 + 16 * t + l15];

  coeff_load(0);
  coeff_store(0);
#pragma unroll
  for (int t = 0; t < 2; ++t)
#pragma unroll
    for (int r = 0; r < 4; ++r)
      zbuf[0][q * 4 + r][n0 + 16 * t + l15] = f2bf(zr[t * 4 + r]);
  barrier_lgkm();

  int cur = 0;

  // ---------------- main time loop ----------------
#pragma unroll 1
  for (int u = 0; u < 256; ++u) {
    const int   p   = u >> 2;
    const int   sub = u & 3;
    const float s0  = 0.25f * (float)sub;

    // this step's coeffs -> regs (c1,c2,c3 per element)
    float c1v[8], c2v[8], c3v[8];
#pragma unroll
    for (int t = 0; t < 2; ++t)
#pragma unroll
      for (int r = 0; r < 4; ++r) {
        const int e = t * 4 + r;
        const f32x4 cv =
            *(const f32x4*)&cbuf[p & 1][(size_t)((q * 4 + r) * 128 + n0 + 16 * t + l15) * 4];
        c1v[e] = cv[1]; c2v[e] = cv[2]; c3v[e] = cv[3];
      }

    if (sub == 0 && p < 63) coeff_load(p + 1);  // issue next-piece prefetch early

    float sacc[8], kx[8];

    auto do_layer = [&](const bf16x8(&wf)[2][4], f32x4& A0, f32x4& A1) {
      const unsigned short(&zi)[16][136] = zbuf[cur];
      // A-frag: A[m][k], m = lane&15, k = (lane>>4)*8 + i, contiguous 16B
      bf16x8 a0 = *(const bf16x8*)&zi[l15][0 + q * 8];
      bf16x8 a1 = *(const bf16x8*)&zi[l15][32 + q * 8];
      bf16x8 a2 = *(const bf16x8*)&zi[l15][64 + q * 8];
      bf16x8 a3 = *(const bf16x8*)&zi[l15][96 + q * 8];
      A0 = MFMA16(a0, wf[0][0], A0); A1 = MFMA16(a0, wf[1][0], A1);
      A0 = MFMA16(a1, wf[0][1], A0); A1 = MFMA16(a1, wf[1][1], A1);
      A0 = MFMA16(a2, wf[0][2], A0); A1 = MFMA16(a2, wf[1][2], A1);
      A0 = MFMA16(a3, wf[0][3], A0); A1 = MFMA16(a3, wf[1][3], A1);
    };

    auto store_h = [&](f32x4 A0, f32x4 A1, float bb0, float bb1, int act) {
#pragma unroll
      for (int r = 0; r < 4; ++r) {
        float v0 = A0[r] + bb0;
        float v1 = A1[r] + bb1;
        if (act == 1) { v0 = v0 > 0.f ? v0 : expm1f(v0); v1 = v1 > 0.f ? v1 : expm1f(v1); }
        else if (act == 2) { v0 = fmaxf(v0, 0.f); v1 = fmaxf(v1, 0.f); }
        zbuf[cur ^ 1][q * 4 + r][n0 + l15]      = f2bf(v0);
        zbuf[cur ^ 1][q * 4 + r][n0 + 16 + l15] = f2bf(v1);
      }
    };

    // one MLP evaluation f(input in zbuf[cur]); result (pre-dX) left in kx[]
    auto run_f = [&](bool wr_coeff) {
      f32x4 A0 = {0.f, 0.f, 0.f, 0.f}, A1 = {0.f, 0.f, 0.f, 0.f};
      do_layer(wf1, A0, A1);
      store_h(A0, A1, bs1[0], bs1[1], 1);         // ELU
      barrier_lgkm(); cur ^= 1;
      A0 = f32x4{0.f, 0.f, 0.f, 0.f}; A1 = f32x4{0.f, 0.f, 0.f, 0.f};
      do_layer(wf2, A0, A1);
      store_h(A0, A1, bs2[0], bs2[1], 2);         // ReLU
      if (wr_coeff) coeff_store(p + 1);           // T14: write-late, before this barrier
      barrier_lgkm(); cur ^= 1;
      A0 = f32x4{0.f, 0.f, 0.f, 0.f}; A1 = f32x4{0.f, 0.f, 0.f, 0.f};
      do_layer(wf3, A0, A1);
#pragma unroll
      for (int r = 0; r < 4; ++r) { kx[r] = A0[r] + bs3[0]; kx[4 + r] = A1[r] + bs3[1]; }
    };

    // ---- stage 1: k1 = f(z) * dX(s0) ----
    run_f(false);
#pragma unroll
    for (int e = 0; e < 8; ++e) {
      const float dx = c1v[e] + (2.f * c2v[e] + 3.f * c3v[e] * s0) * s0;
      kx[e] *= dx;
      sacc[e] = kx[e];
    }
#pragma unroll
    for (int t = 0; t < 2; ++t)
#pragma unroll
      for (int r = 0; r < 4; ++r)
        zbuf[cur ^ 1][q * 4 + r][n0 + 16 * t + l15] = f2bf(zr[t * 4 + r] + 0.125f * kx[t * 4 + r]);
    barrier_lgkm(); cur ^= 1;

    // ---- stage 2: k2 = f(z + dt/2 k1) * dX(s0 + 0.125) ----
    run_f(false);
    {
      const float sb = s0 + 0.125f;
#pragma unroll
      for (int e = 0; e < 8; ++e) {
        const float dx = c1v[e] + (2.f * c2v[e] + 3.f * c3v[e] * sb) * sb;
        kx[e] *= dx;
        sacc[e] += 2.f * kx[e];
      }
    }
#pragma unroll
    for (int t = 0; t < 2; ++t)
#pragma unroll
      for (int r = 0; r < 4; ++r)
        zbuf[cur ^ 1][q * 4 + r][n0 + 16 * t + l15] = f2bf(zr[t * 4 + r] + 0.125f * kx[t * 4 + r]);
    barrier_lgkm(); cur ^= 1;

    // ---- stage 3: k3 = f(z + dt/2 k2) * dX(s0 + 0.125) ----
    run_f(false);
    {
      const float sb = s0 + 0.125f;
#pragma unroll
      for (int e = 0; e < 8; ++e) {
        const float dx = c1v[e] + (2.f * c2v[e] + 3.f * c3v[e] * sb) * sb;
        kx[e] *= dx;
        sacc[e] += 2.f * kx[e];
      }
    }
#pragma unroll
    for (int t = 0; t < 2; ++t)
#pragma unroll
      for (int r = 0; r < 4; ++r)
        zbuf[cur ^ 1][q * 4 + r][n0 + 16 * t + l15] = f2bf(zr[t * 4 + r] + 0.25f * kx[t * 4 + r]);
    barrier_lgkm(); cur ^= 1;

    // ---- stage 4: k4 = f(z + dt k3) * dX(t + dt) ----
    run_f(sub == 3 && p < 63);  // next-piece coeffs land in LDS inside (before barrier)
    if (sub == 3) {
      if (p < 63) {
        // t+dt starts the NEXT piece: dX = c1(next piece) (s = 0)
#pragma unroll
        for (int t = 0; t < 2; ++t)
#pragma unroll
          for (int r = 0; r < 4; ++r) {
            const int e = t * 4 + r;
            const float dx =
                cbuf[(p + 1) & 1][(size_t)((q * 4 + r) * 128 + n0 + 16 * t + l15) * 4 + 1];
            kx[e] *= dx;
          }
      } else {
        // u = 255: t+dt = 64 clips to piece 63 at s = 1
#pragma unroll
        for (int e = 0; e < 8; ++e) {
          const float dx = c1v[e] + 2.f * c2v[e] + 3.f * c3v[e];
          kx[e] *= dx;
        }
      }
    } else {
      const float sc = s0 + 0.25f;
#pragma unroll
      for (int e = 0; e < 8; ++e) {
        const float dx = c1v[e] + (2.f * c2v[e] + 3.f * c3v[e] * sc) * sc;
        kx[e] *= dx;
      }
    }
#pragma unroll
    for (int e = 0; e < 8; ++e) {
      sacc[e] += kx[e];
      zr[e] += (0.25f / 6.0f) * sacc[e];
    }
#pragma unroll
    for (int t = 0; t < 2; ++t)
#pragma unroll
      for (int r = 0; r < 4; ++r)
        zbuf[cur ^ 1][q * 4 + r][n0 + 16 * t + l15] = f2bf(zr[t * 4 + r]);
    barrier_lgkm(); cur ^= 1;
  }

  // ---------------- readout: out = zT @ Wr + br ----------------
  barrier_lgkm();
  {
    float* zf = cbuf[0];  // reuse as [16][132] fp32
#pragma unroll
    for (int t = 0; t < 2; ++t)
#pragma unroll
      for (int r = 0; r < 4; ++r)
        zf[(q * 4 + r) * 132 + n0 + 16 * t + l15] = zr[t * 4 + r];
  }
  barrier_lgkm();
  if (tid < 160) {
    const int row = tid / 10, o = tid - row * 10;
    const float* zf = cbuf[0];
    float acc = br[o];
#pragma unroll 4
    for (int ch = 0; ch < 128; ++ch)
      acc = fmaf(zf[row * 132 + ch], Wr[ch * 10 + o], acc);
    out[(size_t)(row0 + row) * 10 + o] = acc;
  }
}

extern "C" void kernel_launch(void* const* d_in, const int* in_sizes, int n_in,
                              void* d_out, int out_size, void* d_ws, size_t ws_size,
                              hipStream_t stream) {
  const float* z0     = (const float*)d_in[0];
  const float* coeffs = (const float*)d_in[1];
  const float* W1 = (const float*)d_in[2]; const float* b1 = (const float*)d_in[3];
  const float* W2 = (const float*)d_in[4]; const float* b2 = (const float*)d_in[5];
  const float* W3 = (const float*)d_in[6]; const float* b3 = (const float*)d_in[7];
  const float* Wr = (const float*)d_in[8]; const float* br = (const float*)d_in[9];
  hipLaunchKernelGGL(cde_fused, dim3(256), dim3(256), 0, stream,
                     z0, coeffs, W1, b1, W2, b2, W3, b3, Wr, br, (float*)d_out);
}

// Round 2
// 881.339 us; speedup vs baseline: 1.6646x; 1.6646x over previous
//
#include <hip/hip_runtime.h>
#include <hip/hip_bf16.h>
#include <math.h>

// NeuralCDE fused kernel, round 2.
// 256 blocks x 512 threads (8 waves). Each block owns 16 batch rows for the
// full 256-step RK4 integration. Wave w owns output channels [16w,16w+16):
// weights held in VGPRs (48 regs), activations ping-pong through an 8.7 KB
// bf16 LDS buffer, spline coefficients gather-loaded straight into registers
// (no LDS staging), z/k/acc fp32 in registers.

typedef short bf16x8 __attribute__((ext_vector_type(8)));
typedef float f32x4  __attribute__((ext_vector_type(4)));

#define MFMA16(a, b, c) __builtin_amdgcn_mfma_f32_16x16x32_bf16((a), (b), (c), 0, 0, 0)

__device__ __forceinline__ unsigned short f2bf(float x) {
  unsigned int u = __float_as_uint(x);
  u += 0x7FFFu + ((u >> 16) & 1u);   // round-to-nearest-even
  return (unsigned short)(u >> 16);
}

// raw barrier: LDS-drain only (keeps global prefetch loads in flight).
__device__ __forceinline__ void barrier_lgkm() {
  asm volatile("s_waitcnt lgkmcnt(0)" ::: "memory");
  __builtin_amdgcn_s_barrier();
  asm volatile("" ::: "memory");
}

__global__ __launch_bounds__(512, 2) void cde_fused(
    const float* __restrict__ z0, const float* __restrict__ coeffs,
    const float* __restrict__ W1, const float* __restrict__ b1,
    const float* __restrict__ W2, const float* __restrict__ b2,
    const float* __restrict__ W3, const float* __restrict__ b3,
    const float* __restrict__ Wr, const float* __restrict__ br,
    float* __restrict__ out) {
  // 136-short row stride: A-frag b128 reads land 8 dwords/bank (optimal),
  // scalar bf16 stores are 2-way (free).
  __shared__ __align__(16) unsigned short zbuf[2][16][136];

  const int tid  = (int)threadIdx.x;
  const int lane = tid & 63;
  const int wv   = tid >> 6;   // wave 0..7
  const int l15  = lane & 15;
  const int q    = lane >> 4;  // 0..3
  const int nb   = wv * 16;    // this wave's output-channel base
  const int n    = nb + l15;   // this lane's output channel
  const int row0 = (int)blockIdx.x * 16;

  // ---------------- weight fragments (one-time, 48 VGPRs) ----------------
  // B-frag for 16x16x32: B[k][n], n = lane&15, k = (lane>>4)*8 + i
  bf16x8 wf1[4], wf2[4], wf3[4];
  const float bs1 = b1[n], bs2 = b2[n], bs3 = b3[n];
#pragma unroll
  for (int ks = 0; ks < 4; ++ks) {
    bf16x8 fa, fb, fc;
#pragma unroll
    for (int i = 0; i < 8; ++i) {
      const int k = ks * 32 + q * 8 + i;
      fa[i] = (short)f2bf(W1[k * 128 + n]);
      fb[i] = (short)f2bf(W2[k * 128 + n]);
      fc[i] = (short)f2bf(W3[k * 128 + n]);
    }
    wf1[ks] = fa; wf2[ks] = fb; wf3[ks] = fc;
  }

  // ---------------- coeff registers (no LDS) ----------------
  // element r -> (local row q*4+r, channel n); cf = piece prefetch buffer
  f32x4 cf[4];
  auto coeff_load = [&](int p) {
#pragma unroll
    for (int r = 0; r < 4; ++r)
      cf[r] = *(const f32x4*)(coeffs + ((size_t)((row0 + q * 4 + r) * 64 + p) * 128 + n) * 4);
  };
  float c1v[4], c2v[4], c3v[4];
  auto coeff_adopt = [&]() {
#pragma unroll
    for (int r = 0; r < 4; ++r) { c1v[r] = cf[r][1]; c2v[r] = cf[r][2]; c3v[r] = cf[r][3]; }
  };

  // ---------------- prologue ----------------
  float zr[4];  // fp32 state, D-frag layout: r -> (row q*4+r, ch n)
#pragma unroll
  for (int r = 0; r < 4; ++r)
    zr[r] = z0[(size_t)(row0 + q * 4 + r) * 128 + n];

  coeff_load(0);
  coeff_adopt();
#pragma unroll
  for (int r = 0; r < 4; ++r)
    zbuf[0][q * 4 + r][n] = f2bf(zr[r]);
  barrier_lgkm();

  int cur = 0;
  float sacc[4], kx[4];

  auto do_layer = [&](const bf16x8(&wf)[4], f32x4& A) {
    const unsigned short(&zi)[16][136] = zbuf[cur];
    // A-frag: A[m][k], m = lane&15, k = (lane>>4)*8 + i (contiguous 16B)
    bf16x8 a0 = *(const bf16x8*)&zi[l15][0 + q * 8];
    bf16x8 a1 = *(const bf16x8*)&zi[l15][32 + q * 8];
    bf16x8 a2 = *(const bf16x8*)&zi[l15][64 + q * 8];
    bf16x8 a3 = *(const bf16x8*)&zi[l15][96 + q * 8];
    f32x4 Aa = {0.f, 0.f, 0.f, 0.f}, Ab = {0.f, 0.f, 0.f, 0.f};
    Aa = MFMA16(a0, wf[0], Aa); Ab = MFMA16(a1, wf[1], Ab);   // 2 indep chains
    Aa = MFMA16(a2, wf[2], Aa); Ab = MFMA16(a3, wf[3], Ab);
    A = Aa + Ab;
  };

  auto store_h = [&](f32x4 A, float bb, int act) {
#pragma unroll
    for (int r = 0; r < 4; ++r) {
      float v = A[r] + bb;
      if (act == 1) v = v > 0.f ? v : (__expf(v) - 1.0f);   // ELU (fast exp)
      else if (act == 2) v = fmaxf(v, 0.f);                 // ReLU
      zbuf[cur ^ 1][q * 4 + r][n] = f2bf(v);
    }
  };

  auto run_f = [&]() {  // one MLP eval of zbuf[cur]; pre-dX result -> kx
    f32x4 A;
    do_layer(wf1, A);
    store_h(A, bs1, 1);
    barrier_lgkm(); cur ^= 1;
    do_layer(wf2, A);
    store_h(A, bs2, 2);
    barrier_lgkm(); cur ^= 1;
    do_layer(wf3, A);
#pragma unroll
    for (int r = 0; r < 4; ++r) kx[r] = A[r] + bs3;
  };

  auto store_z = [&](float scale) {  // write z + scale*kx as next f-input
#pragma unroll
    for (int r = 0; r < 4; ++r)
      zbuf[cur ^ 1][q * 4 + r][n] = f2bf(zr[r] + scale * kx[r]);
  };

  // ---------------- main time loop ----------------
#pragma unroll 1
  for (int u = 0; u < 256; ++u) {
    const int   p   = u >> 2;
    const int   sub = u & 3;
    const float s0  = 0.25f * (float)sub;

    if (sub == 0 && p < 63) coeff_load(p + 1);  // prefetch next piece into regs

    // ---- stage 1: k1 = f(z) * dX(s0) ----
    run_f();
#pragma unroll
    for (int r = 0; r < 4; ++r) {
      const float dx = c1v[r] + (2.f * c2v[r] + 3.f * c3v[r] * s0) * s0;
      kx[r] *= dx;
      sacc[r] = kx[r];
    }
    store_z(0.125f);
    barrier_lgkm(); cur ^= 1;

    // ---- stage 2: k2 = f(z + dt/2 k1) * dX(s0 + 0.125) ----
    run_f();
    {
      const float sb = s0 + 0.125f;
#pragma unroll
      for (int r = 0; r < 4; ++r) {
        const float dx = c1v[r] + (2.f * c2v[r] + 3.f * c3v[r] * sb) * sb;
        kx[r] *= dx;
        sacc[r] += 2.f * kx[r];
      }
    }
    store_z(0.125f);
    barrier_lgkm(); cur ^= 1;

    // ---- stage 3: k3 = f(z + dt/2 k2) * dX(s0 + 0.125) ----
    run_f();
    {
      const float sb = s0 + 0.125f;
#pragma unroll
      for (int r = 0; r < 4; ++r) {
        const float dx = c1v[r] + (2.f * c2v[r] + 3.f * c3v[r] * sb) * sb;
        kx[r] *= dx;
        sacc[r] += 2.f * kx[r];
      }
    }
    store_z(0.25f);
    barrier_lgkm(); cur ^= 1;

    // ---- stage 4: k4 = f(z + dt k3) * dX(t + dt) ----
    run_f();
    if (sub == 3) {
      if (p < 63) {
        // t+dt starts the NEXT piece: dX = c1(next piece) at s = 0 (from cf regs)
#pragma unroll
        for (int r = 0; r < 4; ++r) kx[r] *= cf[r][1];
      } else {
        // u = 255: t+dt = 64 clips to piece 63 at s = 1
#pragma unroll
        for (int r = 0; r < 4; ++r) kx[r] *= (c1v[r] + 2.f * c2v[r] + 3.f * c3v[r]);
      }
    } else {
      const float sc = s0 + 0.25f;
#pragma unroll
      for (int r = 0; r < 4; ++r)
        kx[r] *= c1v[r] + (2.f * c2v[r] + 3.f * c3v[r] * sc) * sc;
    }
#pragma unroll
    for (int r = 0; r < 4; ++r) {
      sacc[r] += kx[r];
      zr[r] += (0.25f / 6.0f) * sacc[r];
    }
#pragma unroll
    for (int r = 0; r < 4; ++r)
      zbuf[cur ^ 1][q * 4 + r][n] = f2bf(zr[r]);
    barrier_lgkm(); cur ^= 1;

    if (sub == 3 && p < 63) coeff_adopt();  // next piece's c1,c2,c3 -> live regs
  }

  // ---------------- readout: out = zT @ Wr + br ----------------
  // reuse zbuf as fp32 scratch [16][132] (8448 B <= 8704 B)
  {
    float* zf = (float*)&zbuf[0][0][0];
#pragma unroll
    for (int r = 0; r < 4; ++r)
      zf[(q * 4 + r) * 132 + n] = zr[r];
  }
  barrier_lgkm();
  if (tid < 160) {
    const int row = tid / 10, o = tid - row * 10;
    const float* zf = (const float*)&zbuf[0][0][0];
    float acc = br[o];
#pragma unroll 4
    for (int ch = 0; ch < 128; ++ch)
      acc = fmaf(zf[row * 132 + ch], Wr[ch * 10 + o], acc);
    out[(size_t)(row0 + row) * 10 + o] = acc;
  }
}

extern "C" void kernel_launch(void* const* d_in, const int* in_sizes, int n_in,
                              void* d_out, int out_size, void* d_ws, size_t ws_size,
                              hipStream_t stream) {
  const float* z0     = (const float*)d_in[0];
  const float* coeffs = (const float*)d_in[1];
  const float* W1 = (const float*)d_in[2]; const float* b1 = (const float*)d_in[3];
  const float* W2 = (const float*)d_in[4]; const float* b2 = (const float*)d_in[5];
  const float* W3 = (const float*)d_in[6]; const float* b3 = (const float*)d_in[7];
  const float* Wr = (const float*)d_in[8]; const float* br = (const float*)d_in[9];
  hipLaunchKernelGGL(cde_fused, dim3(256), dim3(512), 0, stream,
                     z0, coeffs, W1, b1, W2, b2, W3, b3, Wr, br, (float*)d_out);
}

// Round 3
// 879.670 us; speedup vs baseline: 1.6677x; 1.0019x over previous
//
#include <hip/hip_runtime.h>
#include <hip/hip_bf16.h>
#include <math.h>

// NeuralCDE fused kernel, round 3.
// 256 blocks x 512 threads (8 waves); block owns 16 batch rows for all 256
// RK4 steps. Wave w owns output channels [16w,16w+16). Weights in VGPRs,
// activations ping-pong through a swizzled 8.7KB bf16 LDS buffer (XOR bit5
// with row bit3 kills the 4-way store conflicts), coeffs register-prefetched.
// All LDS addresses are loop-invariant (static buffer parity per segment).

typedef short bf16x8 __attribute__((ext_vector_type(8)));
typedef float f32x4  __attribute__((ext_vector_type(4)));

#define MFMA16(a, b, c) __builtin_amdgcn_mfma_f32_16x16x32_bf16((a), (b), (c), 0, 0, 0)

__device__ __forceinline__ unsigned short f2bf(float x) {
  unsigned int u = __float_as_uint(x);
  u += 0x7FFFu + ((u >> 16) & 1u);   // round-to-nearest-even
  return (unsigned short)(u >> 16);
}

// raw barrier: LDS-drain only (keeps global prefetch loads in flight).
__device__ __forceinline__ void barrier_lgkm() {
  asm volatile("s_waitcnt lgkmcnt(0)" ::: "memory");
  __builtin_amdgcn_s_barrier();
  asm volatile("" ::: "memory");
}

__global__ __launch_bounds__(512, 2) void cde_fused(
    const float* __restrict__ z0, const float* __restrict__ coeffs,
    const float* __restrict__ W1, const float* __restrict__ b1,
    const float* __restrict__ W2, const float* __restrict__ b2,
    const float* __restrict__ W3, const float* __restrict__ b3,
    const float* __restrict__ Wr, const float* __restrict__ br,
    float* __restrict__ out) {
  // [2][16][136] shorts; byte addr of (buf,row,ch) = buf*4352 + row*272 + ch*2,
  // then XOR (row&8)<<2 (flip bit5 with row bit3). Verified collision-free.
  __shared__ __align__(16) unsigned short zbuf[2][16][136];
  char* const lds = (char*)&zbuf[0][0][0];

  const int tid  = (int)threadIdx.x;
  const int lane = tid & 63;
  const int wv   = tid >> 6;   // wave 0..7
  const int l15  = lane & 15;
  const int q    = lane >> 4;  // 0..3
  const int n    = wv * 16 + l15;   // this lane's output channel
  const int row0 = (int)blockIdx.x * 16;

  // ---- hoisted swizzled LDS addresses (all further offsets are immediates) --
  // A-frag read: row = l15, ch = 8q + 32j  -> base + 64j (+4352*buf)
  const int rd0 = (l15 * 272 + q * 16) ^ ((l15 & 8) << 2);
  // store: row = 4q+r, ch = n  (r = 0..3 static in unrolled loops)
  int wroff[4];
#pragma unroll
  for (int r = 0; r < 4; ++r)
    wroff[r] = (q * 1088 + r * 272 + wv * 32 + l15 * 2) ^ ((q & 2) << 4);

  // ---------------- weight fragments (one-time, 48 VGPRs) ----------------
  // B-frag 16x16x32: B[k][n], n = lane&15, k = (lane>>4)*8 + i
  bf16x8 wf1[4], wf2[4], wf3[4];
  const float bs1 = b1[n], bs2 = b2[n], bs3 = b3[n];
#pragma unroll
  for (int ks = 0; ks < 4; ++ks) {
    bf16x8 fa, fb, fc;
#pragma unroll
    for (int i = 0; i < 8; ++i) {
      const int k = ks * 32 + q * 8 + i;
      fa[i] = (short)f2bf(W1[k * 128 + n]);
      fb[i] = (short)f2bf(W2[k * 128 + n]);
      fc[i] = (short)f2bf(W3[k * 128 + n]);
    }
    wf1[ks] = fa; wf2[ks] = fb; wf3[ks] = fc;
  }

  // ---------------- coeff registers (no LDS) ----------------
  f32x4 cf[4];  // element r -> (batch row row0+4q+r, channel n)
  auto coeff_load = [&](int p) {
#pragma unroll
    for (int r = 0; r < 4; ++r)
      cf[r] = *(const f32x4*)(coeffs + ((size_t)((row0 + q * 4 + r) * 64 + p) * 128 + n) * 4);
  };
  float c1v[4], c2b[4], c3b[4];   // c1, 2*c2, 3*c3
  auto coeff_adopt = [&]() {
#pragma unroll
    for (int r = 0; r < 4; ++r) {
      c1v[r] = cf[r][1]; c2b[r] = 2.f * cf[r][2]; c3b[r] = 3.f * cf[r][3];
    }
  };

  auto st16 = [&](int wb, int r, float v) {
    *(unsigned short*)(lds + (wb * 4352 + wroff[r])) = f2bf(v);
  };

  // ---------------- prologue ----------------
  float zr[4];  // fp32 state, D-frag layout: r -> (row 4q+r, ch n)
#pragma unroll
  for (int r = 0; r < 4; ++r)
    zr[r] = z0[(size_t)(row0 + q * 4 + r) * 128 + n];

  coeff_load(0);
  coeff_adopt();
#pragma unroll
  for (int r = 0; r < 4; ++r) st16(0, r, zr[r]);
  barrier_lgkm();

  float kx[4], sacc[4];

  auto layer = [&](const bf16x8(&wf)[4], f32x4& A, int rb) {
    const char* base = lds + rb * 4352 + rd0;
    bf16x8 a0 = *(const bf16x8*)(base);
    bf16x8 a1 = *(const bf16x8*)(base + 64);
    bf16x8 a2 = *(const bf16x8*)(base + 128);
    bf16x8 a3 = *(const bf16x8*)(base + 192);
    f32x4 Aa = {0.f, 0.f, 0.f, 0.f}, Ab = {0.f, 0.f, 0.f, 0.f};
    Aa = MFMA16(a0, wf[0], Aa); Ab = MFMA16(a1, wf[1], Ab);   // 2 indep chains
    Aa = MFMA16(a2, wf[2], Aa); Ab = MFMA16(a3, wf[3], Ab);
    A = Aa + Ab;
  };

  // one MLP eval; input in buffer sp; pre-dX result -> kx. Buffer parity:
  // L1 rd sp -> wr sp^1 | L2 rd sp^1 -> wr sp | L3 rd sp
  auto run_f = [&](int sp) {
    f32x4 A;
    layer(wf1, A, sp);
#pragma unroll
    for (int r = 0; r < 4; ++r) {
      float v = A[r] + bs1;
      v = v > 0.f ? v : (__expf(v) - 1.f);          // ELU
      st16(sp ^ 1, r, v);
    }
    barrier_lgkm();
    layer(wf2, A, sp ^ 1);
#pragma unroll
    for (int r = 0; r < 4; ++r)
      st16(sp, r, fmaxf(A[r] + bs2, 0.f));          // ReLU
    barrier_lgkm();
    layer(wf3, A, sp);
#pragma unroll
    for (int r = 0; r < 4; ++r) kx[r] = A[r] + bs3;
  };

  // ---------------- main time loop ----------------
#pragma unroll 1
  for (int u = 0; u < 256; ++u) {
    const int   p   = u >> 2;
    const int   sub = u & 3;
    const float s0  = 0.25f * (float)sub;

    if (sub == 0 && p < 63) coeff_load(p + 1);  // prefetch next piece into regs

    // ---- stage 1: k1 = f(z) * dX(s0); z-input in buf0 ----
    run_f(0);
#pragma unroll
    for (int r = 0; r < 4; ++r) {
      const float dx = c1v[r] + (c2b[r] + c3b[r] * s0) * s0;
      kx[r] *= dx; sacc[r] = kx[r];
      st16(1, r, zr[r] + 0.125f * kx[r]);
    }
    barrier_lgkm();

    // ---- stage 2: k2 at s0+0.125; input buf1 ----
    run_f(1);
    {
      const float sb = s0 + 0.125f;
#pragma unroll
      for (int r = 0; r < 4; ++r) {
        const float dx = c1v[r] + (c2b[r] + c3b[r] * sb) * sb;
        kx[r] *= dx; sacc[r] += 2.f * kx[r];
        st16(0, r, zr[r] + 0.125f * kx[r]);
      }
    }
    barrier_lgkm();

    // ---- stage 3: k3 at s0+0.125; input buf0 ----
    run_f(0);
    {
      const float sb = s0 + 0.125f;
#pragma unroll
      for (int r = 0; r < 4; ++r) {
        const float dx = c1v[r] + (c2b[r] + c3b[r] * sb) * sb;
        kx[r] *= dx; sacc[r] += 2.f * kx[r];
        st16(1, r, zr[r] + 0.25f * kx[r]);
      }
    }
    barrier_lgkm();

    // ---- stage 4: k4 at t+dt; input buf1 ----
    run_f(1);
    if (sub == 3) {
      if (p < 63) {
        // t+dt starts the NEXT piece: dX = c1(next) at s=0 (prefetched regs)
#pragma unroll
        for (int r = 0; r < 4; ++r) kx[r] *= cf[r][1];
      } else {
        // u = 255: t+dt = 64 clips to piece 63 at s = 1
#pragma unroll
        for (int r = 0; r < 4; ++r) kx[r] *= (c1v[r] + c2b[r] + c3b[r]);
      }
    } else {
      const float sc = s0 + 0.25f;
#pragma unroll
      for (int r = 0; r < 4; ++r)
        kx[r] *= c1v[r] + (c2b[r] + c3b[r] * sc) * sc;
    }
#pragma unroll
    for (int r = 0; r < 4; ++r) {
      sacc[r] += kx[r];
      zr[r] += (0.25f / 6.f) * sacc[r];
      st16(0, r, zr[r]);       // next step's f-input -> buf0
    }
    barrier_lgkm();

    if (sub == 3 && p < 63) coeff_adopt();
  }

  // ---------------- readout: out = zT @ Wr + br ----------------
  // reuse LDS as fp32 scratch [16][132] (8448 B <= 8704 B), unswizzled
  {
    float* zf = (float*)lds;
#pragma unroll
    for (int r = 0; r < 4; ++r)
      zf[(q * 4 + r) * 132 + n] = zr[r];
  }
  barrier_lgkm();
  if (tid < 160) {
    const int row = tid / 10, o = tid - row * 10;
    const float* zf = (const float*)lds;
    float acc = br[o];
#pragma unroll 4
    for (int ch = 0; ch < 128; ++ch)
      acc = fmaf(zf[row * 132 + ch], Wr[ch * 10 + o], acc);
    out[(size_t)(row0 + row) * 10 + o] = acc;
  }
}

extern "C" void kernel_launch(void* const* d_in, const int* in_sizes, int n_in,
                              void* d_out, int out_size, void* d_ws, size_t ws_size,
                              hipStream_t stream) {
  const float* z0     = (const float*)d_in[0];
  const float* coeffs = (const float*)d_in[1];
  const float* W1 = (const float*)d_in[2]; const float* b1 = (const float*)d_in[3];
  const float* W2 = (const float*)d_in[4]; const float* b2 = (const float*)d_in[5];
  const float* W3 = (const float*)d_in[6]; const float* b3 = (const float*)d_in[7];
  const float* Wr = (const float*)d_in[8]; const float* br = (const float*)d_in[9];
  hipLaunchKernelGGL(cde_fused, dim3(256), dim3(512), 0, stream,
                     z0, coeffs, W1, b1, W2, b2, W3, b3, Wr, br, (float*)d_out);
}

// Round 4
// 823.360 us; speedup vs baseline: 1.7818x; 1.0684x over previous
//
#include <hip/hip_runtime.h>
#include <hip/hip_bf16.h>
#include <math.h>

// NeuralCDE fused kernel, round 4.
// 256 blocks x 512 threads (8 waves); block owns 16 batch rows for all 256
// RK4 steps. Operand-swapped MFMA: Y^T = W^T (A-operand, regs) * X^T
// (B-operand, LDS b128 reads). D-frag is channel-contiguous per lane ->
// activations stored with cvt_pk_bf16 + ds_write_b64; bias folded into the
// MFMA accumulator init. Coeffs register-prefetched as f32x4. Sub-steps
// fully unrolled (compile-time s0).

typedef short bf16x8 __attribute__((ext_vector_type(8)));
typedef float f32x4  __attribute__((ext_vector_type(4)));
typedef unsigned int u32x2 __attribute__((ext_vector_type(2)));

#define MFMA16(a, b, c) __builtin_amdgcn_mfma_f32_16x16x32_bf16((a), (b), (c), 0, 0, 0)

__device__ __forceinline__ unsigned short f2bf(float x) {  // weight prep only
  unsigned int u = __float_as_uint(x);
  u += 0x7FFFu + ((u >> 16) & 1u);
  return (unsigned short)(u >> 16);
}

__device__ __forceinline__ unsigned int cvt_pk(float lo, float hi) {
  unsigned int r;  // D[15:0]=bf16(lo), D[31:16]=bf16(hi), RNE
  asm("v_cvt_pk_bf16_f32 %0, %1, %2" : "=v"(r) : "v"(lo), "v"(hi));
  return r;
}

// raw barrier: LDS-drain only (keeps global prefetch loads in flight).
__device__ __forceinline__ void barrier_lgkm() {
  asm volatile("s_waitcnt lgkmcnt(0)" ::: "memory");
  __builtin_amdgcn_s_barrier();
  asm volatile("" ::: "memory");
}

__global__ __launch_bounds__(512, 2) void cde_fused(
    const float* __restrict__ z0, const float* __restrict__ coeffs,
    const float* __restrict__ W1, const float* __restrict__ b1,
    const float* __restrict__ W2, const float* __restrict__ b2,
    const float* __restrict__ W3, const float* __restrict__ b3,
    const float* __restrict__ Wr, const float* __restrict__ br,
    float* __restrict__ out) {
  // [2][16 rows][136 ch] shorts; row stride 272 B.
  __shared__ __align__(16) unsigned short zbuf[2][16][136];
  char* const lds = (char*)&zbuf[0][0][0];

  const int tid  = (int)threadIdx.x;
  const int lane = tid & 63;
  const int wv   = tid >> 6;        // wave 0..7
  const int l15  = lane & 15;       // batch row within tile
  const int q    = lane >> 4;       // 0..3
  const int n16  = wv * 16 + l15;   // weight column for this lane's frags
  const int nb4  = wv * 16 + q * 4; // this lane's 4 output channels
  const int row0 = (int)blockIdx.x * 16;

  // B-frag read (X^T): row l15, ch 32ks+8q.. -> byte l15*272 + 64ks + 16q
  const int rdbyte = l15 * 272 + q * 16;
  // D store: row l15, ch nb4.. -> byte l15*272 + nb4*2 (8B aligned)
  const int wrbyte = l15 * 272 + nb4 * 2;

  // ------------- weight A-frags (one-time, 48 VGPRs) -------------
  // A[m][k]: lane(q,l15) holds W^T[16wv+l15][32ks+8q+i] = W[32ks+8q+i][n16]
  bf16x8 wf1[4], wf2[4], wf3[4];
#pragma unroll
  for (int ks = 0; ks < 4; ++ks) {
    bf16x8 fa, fb, fc;
#pragma unroll
    for (int i = 0; i < 8; ++i) {
      const int k = ks * 32 + q * 8 + i;
      fa[i] = (short)f2bf(W1[k * 128 + n16]);
      fb[i] = (short)f2bf(W2[k * 128 + n16]);
      fc[i] = (short)f2bf(W3[k * 128 + n16]);
    }
    wf1[ks] = fa; wf2[ks] = fb; wf3[ks] = fc;
  }
  // biases for this lane's 4 channels (enter MFMA via accumulator init)
  const f32x4 bv1 = *(const f32x4*)(b1 + nb4);
  const f32x4 bv2 = *(const f32x4*)(b2 + nb4);
  const f32x4 bv3 = *(const f32x4*)(b3 + nb4);

  // ------------- coeff registers (element r -> row l15, ch nb4+r) -------------
  f32x4 cf[4];
  auto coeff_load = [&](int p) {
    const float* cb = coeffs + ((size_t)(row0 + l15) * 64 + p) * 512 + nb4 * 4;
#pragma unroll
    for (int r = 0; r < 4; ++r) cf[r] = *(const f32x4*)(cb + r * 4);
  };
  float c1v[4], c2b[4], c3b[4];  // c1, 2*c2, 3*c3
  auto coeff_adopt = [&]() {
#pragma unroll
    for (int r = 0; r < 4; ++r) {
      c1v[r] = cf[r][1]; c2b[r] = 2.f * cf[r][2]; c3b[r] = 3.f * cf[r][3];
    }
  };

  auto stv = [&](int wb, const f32x4 v) {  // pack 4 ch -> one b64 write
    u32x2 w;
    w[0] = cvt_pk(v[0], v[1]);
    w[1] = cvt_pk(v[2], v[3]);
    *(u32x2*)(lds + (wb * 4352 + wrbyte)) = w;
  };

  // ------------- prologue -------------
  float zr[4];
  {
    const f32x4 z = *(const f32x4*)(z0 + (size_t)(row0 + l15) * 128 + nb4);
#pragma unroll
    for (int r = 0; r < 4; ++r) zr[r] = z[r];
  }
  coeff_load(0);
  coeff_adopt();
  stv(0, f32x4{zr[0], zr[1], zr[2], zr[3]});
  barrier_lgkm();

  float kx[4], sacc[4], dxb[4];

  auto layer = [&](const bf16x8(&wf)[4], const f32x4 bias, int rb) -> f32x4 {
    const char* base = lds + rb * 4352 + rdbyte;
    bf16x8 x0 = *(const bf16x8*)(base);
    bf16x8 x1 = *(const bf16x8*)(base + 64);
    bf16x8 x2 = *(const bf16x8*)(base + 128);
    bf16x8 x3 = *(const bf16x8*)(base + 192);
    f32x4 Aa = {0.f, 0.f, 0.f, 0.f}, Ab = bias;
    Aa = MFMA16(wf[0], x0, Aa); Ab = MFMA16(wf[1], x1, Ab);  // 2 indep chains
    Aa = MFMA16(wf[2], x2, Aa); Ab = MFMA16(wf[3], x3, Ab);
    return Aa + Ab;
  };

  // one MLP eval; input in buffer sp; result (incl. b3) -> kx
  auto run_f = [&](int sp) {
    f32x4 A = layer(wf1, bv1, sp);
    f32x4 h;
#pragma unroll
    for (int r = 0; r < 4; ++r) {  // ELU(v) = max(v, exp(min(v,0))-1)
      const float v = A[r];
      h[r] = fmaxf(v, __expf(fminf(v, 0.f)) - 1.f);
    }
    stv(sp ^ 1, h);
    barrier_lgkm();
    A = layer(wf2, bv2, sp ^ 1);
#pragma unroll
    for (int r = 0; r < 4; ++r) h[r] = fmaxf(A[r], 0.f);  // ReLU
    stv(sp, h);
    barrier_lgkm();
    A = layer(wf3, bv3, sp);
#pragma unroll
    for (int r = 0; r < 4; ++r) kx[r] = A[r];
  };

  // ------------- main loop: 64 pieces x 4 unrolled sub-steps -------------
#pragma unroll 1
  for (int p = 0; p < 64; ++p) {
    const bool pre = p < 63;
    if (pre) coeff_load(p + 1);  // prefetch next piece into regs

#pragma unroll
    for (int sub = 0; sub < 4; ++sub) {
      const float s0 = 0.25f * (float)sub;  // compile-time

      // ---- stage 1: k1 = f(z)*dX(s0); input buf0 ----
      run_f(0);
      {
        f32x4 h;
#pragma unroll
        for (int r = 0; r < 4; ++r) {
          const float dx = c1v[r] + (c2b[r] + c3b[r] * s0) * s0;
          kx[r] *= dx; sacc[r] = kx[r];
          h[r] = zr[r] + 0.125f * kx[r];
        }
        stv(1, h);
      }
      barrier_lgkm();

      // ---- stage 2: k2 at s0+0.125; input buf1 ----
      run_f(1);
      {
        const float sb = s0 + 0.125f;
        f32x4 h;
#pragma unroll
        for (int r = 0; r < 4; ++r) {
          dxb[r] = c1v[r] + (c2b[r] + c3b[r] * sb) * sb;
          kx[r] *= dxb[r]; sacc[r] += 2.f * kx[r];
          h[r] = zr[r] + 0.125f * kx[r];
        }
        stv(0, h);
      }
      barrier_lgkm();

      // ---- stage 3: k3 at same s as k2 (dx reused); input buf0 ----
      run_f(0);
      {
        f32x4 h;
#pragma unroll
        for (int r = 0; r < 4; ++r) {
          kx[r] *= dxb[r]; sacc[r] += 2.f * kx[r];
          h[r] = zr[r] + 0.25f * kx[r];
        }
        stv(1, h);
      }
      barrier_lgkm();

      // ---- stage 4: k4 at t+dt; input buf1 ----
      run_f(1);
      if (sub == 3) {
        if (pre) {
#pragma unroll
          for (int r = 0; r < 4; ++r) kx[r] *= cf[r][1];  // next piece, s=0
        } else {
#pragma unroll
          for (int r = 0; r < 4; ++r) kx[r] *= (c1v[r] + c2b[r] + c3b[r]);  // s=1 clip
        }
      } else {
        const float sc = s0 + 0.25f;
#pragma unroll
        for (int r = 0; r < 4; ++r)
          kx[r] *= c1v[r] + (c2b[r] + c3b[r] * sc) * sc;
      }
      {
        f32x4 h;
#pragma unroll
        for (int r = 0; r < 4; ++r) {
          sacc[r] += kx[r];
          zr[r] += (0.25f / 6.f) * sacc[r];
          h[r] = zr[r];
        }
        stv(0, h);  // next step's f-input -> buf0
      }
      barrier_lgkm();
    }
    if (pre) coeff_adopt();
  }

  // ------------- readout: out = zT @ Wr + br -------------
  // reuse LDS as fp32 [16][132] (8448 B <= 8704 B)
  {
    float* zf = (float*)lds;
    *(f32x4*)(zf + l15 * 132 + nb4) = f32x4{zr[0], zr[1], zr[2], zr[3]};
  }
  barrier_lgkm();
  if (tid < 160) {
    const int row = tid / 10, o = tid - row * 10;
    const float* zf = (const float*)lds;
    float acc = br[o];
#pragma unroll 4
    for (int ch = 0; ch < 128; ++ch)
      acc = fmaf(zf[row * 132 + ch], Wr[ch * 10 + o], acc);
    out[(size_t)(row0 + row) * 10 + o] = acc;
  }
}

extern "C" void kernel_launch(void* const* d_in, const int* in_sizes, int n_in,
                              void* d_out, int out_size, void* d_ws, size_t ws_size,
                              hipStream_t stream) {
  const float* z0     = (const float*)d_in[0];
  const float* coeffs = (const float*)d_in[1];
  const float* W1 = (const float*)d_in[2]; const float* b1 = (const float*)d_in[3];
  const float* W2 = (const float*)d_in[4]; const float* b2 = (const float*)d_in[5];
  const float* W3 = (const float*)d_in[6]; const float* b3 = (const float*)d_in[7];
  const float* Wr = (const float*)d_in[8]; const float* br = (const float*)d_in[9];
  hipLaunchKernelGGL(cde_fused, dim3(256), dim3(512), 0, stream,
                     z0, coeffs, W1, b1, W2, b2, W3, b3, Wr, br, (float*)d_out);
}

// Round 5
// 804.810 us; speedup vs baseline: 1.8228x; 1.0230x over previous
//
#include <hip/hip_runtime.h>
#include <hip/hip_bf16.h>
#include <math.h>

// NeuralCDE fused kernel, round 5.
// 256 blocks x 256 threads (4 waves); block owns 16 batch rows for all 256
// RK4 steps. Each wave owns N=32 output channels (2 M-tiles) -> halves the
// per-segment LDS read amplification vs 8 waves (each ds_read_b128 B-frag
// feeds 2 MFMAs). Operand-swapped MFMA: Y^T = W^T (A, regs) * X^T (B, LDS).
// Bias in accumulator init; activations stored via cvt_pk_bf16+ds_write_b64;
// coeffs register-prefetched; sub-steps fully unrolled.

typedef short bf16x8 __attribute__((ext_vector_type(8)));
typedef float f32x4  __attribute__((ext_vector_type(4)));
typedef unsigned int u32x2 __attribute__((ext_vector_type(2)));

#define MFMA16(a, b, c) __builtin_amdgcn_mfma_f32_16x16x32_bf16((a), (b), (c), 0, 0, 0)

__device__ __forceinline__ unsigned short f2bf(float x) {  // weight prep only
  unsigned int u = __float_as_uint(x);
  u += 0x7FFFu + ((u >> 16) & 1u);
  return (unsigned short)(u >> 16);
}

__device__ __forceinline__ unsigned int cvt_pk(float lo, float hi) {
  unsigned int r;  // D[15:0]=bf16(lo), D[31:16]=bf16(hi), RNE
  asm("v_cvt_pk_bf16_f32 %0, %1, %2" : "=v"(r) : "v"(lo), "v"(hi));
  return r;
}

// raw barrier: LDS-drain only (keeps global prefetch loads in flight).
__device__ __forceinline__ void barrier_lgkm() {
  asm volatile("s_waitcnt lgkmcnt(0)" ::: "memory");
  __builtin_amdgcn_s_barrier();
  asm volatile("" ::: "memory");
}

__global__ __launch_bounds__(256, 1) void cde_fused(
    const float* __restrict__ z0, const float* __restrict__ coeffs,
    const float* __restrict__ W1, const float* __restrict__ b1,
    const float* __restrict__ W2, const float* __restrict__ b2,
    const float* __restrict__ W3, const float* __restrict__ b3,
    const float* __restrict__ Wr, const float* __restrict__ br,
    float* __restrict__ out) {
  // [2][16 rows][136 ch] shorts; row stride 272 B.
  __shared__ __align__(16) unsigned short zbuf[2][16][136];
  char* const lds = (char*)&zbuf[0][0][0];

  const int tid  = (int)threadIdx.x;
  const int lane = tid & 63;
  const int wv   = tid >> 6;        // wave 0..3
  const int l15  = lane & 15;       // batch row within tile
  const int q    = lane >> 4;       // 0..3
  const int cb0  = wv * 32;         // wave's channel base (2 M-tiles of 16)
  const int row0 = (int)blockIdx.x * 16;

  // B-frag read (X^T): row l15, ch 32ks+8q.. -> byte l15*272 + 64ks + 16q
  const int rdbyte = l15 * 272 + q * 16;
  // D store: row l15, ch cb0+16mt+4q.. -> byte (8B aligned)
  const int wrbyte0 = l15 * 272 + (cb0 + 4 * q) * 2;
  const int wrbyte1 = wrbyte0 + 32;

  // ------------- weight A-frags (one-time, 96 VGPRs) -------------
  // A[m][k]: lane(q,l15) of tile mt holds W[32ks+8q+i][cb0+16mt+l15]
  bf16x8 wf1[2][4], wf2[2][4], wf3[2][4];
#pragma unroll
  for (int mt = 0; mt < 2; ++mt) {
    const int col = cb0 + 16 * mt + l15;
#pragma unroll
    for (int ks = 0; ks < 4; ++ks) {
      bf16x8 fa, fb, fc;
#pragma unroll
      for (int i = 0; i < 8; ++i) {
        const int k = ks * 32 + q * 8 + i;
        fa[i] = (short)f2bf(W1[k * 128 + col]);
        fb[i] = (short)f2bf(W2[k * 128 + col]);
        fc[i] = (short)f2bf(W3[k * 128 + col]);
      }
      wf1[mt][ks] = fa; wf2[mt][ks] = fb; wf3[mt][ks] = fc;
    }
  }
  // biases (accumulator init): D element r of tile mt = ch cb0+16mt+4q+r
  f32x4 bv1[2], bv2[2], bv3[2];
#pragma unroll
  for (int mt = 0; mt < 2; ++mt) {
    bv1[mt] = *(const f32x4*)(b1 + cb0 + 16 * mt + 4 * q);
    bv2[mt] = *(const f32x4*)(b2 + cb0 + 16 * mt + 4 * q);
    bv3[mt] = *(const f32x4*)(b3 + cb0 + 16 * mt + 4 * q);
  }

  // ------------- coeff registers (e = mt*4+r -> row l15, ch cb0+16mt+4q+r) ----
  f32x4 cf[8];
  auto coeff_load = [&](int p) {
    const float* cb = coeffs + ((size_t)(row0 + l15) * 64 + p) * 512;
#pragma unroll
    for (int mt = 0; mt < 2; ++mt)
#pragma unroll
      for (int r = 0; r < 4; ++r)
        cf[mt * 4 + r] = *(const f32x4*)(cb + (cb0 + 16 * mt + 4 * q + r) * 4);
  };
  float c1v[8], c2b[8], c3b[8];  // c1, 2*c2, 3*c3
  auto coeff_adopt = [&]() {
#pragma unroll
    for (int e = 0; e < 8; ++e) {
      c1v[e] = cf[e][1]; c2b[e] = 2.f * cf[e][2]; c3b[e] = 3.f * cf[e][3];
    }
  };

  auto stv = [&](int wb, const float (&h)[8]) {  // 8 ch -> two b64 writes
    u32x2 w0, w1;
    w0[0] = cvt_pk(h[0], h[1]); w0[1] = cvt_pk(h[2], h[3]);
    w1[0] = cvt_pk(h[4], h[5]); w1[1] = cvt_pk(h[6], h[7]);
    *(u32x2*)(lds + (wb * 4352 + wrbyte0)) = w0;
    *(u32x2*)(lds + (wb * 4352 + wrbyte1)) = w1;
  };

  // ------------- prologue -------------
  float zr[8];
  {
    const float* zp = z0 + (size_t)(row0 + l15) * 128;
    const f32x4 za = *(const f32x4*)(zp + cb0 + 4 * q);
    const f32x4 zb = *(const f32x4*)(zp + cb0 + 16 + 4 * q);
#pragma unroll
    for (int r = 0; r < 4; ++r) { zr[r] = za[r]; zr[4 + r] = zb[r]; }
  }
  coeff_load(0);
  coeff_adopt();
  {
    float h[8];
#pragma unroll
    for (int e = 0; e < 8; ++e) h[e] = zr[e];
    stv(0, h);
  }
  barrier_lgkm();

  float kx[8], sacc[8], dxb[8];

  // one layer: out[mt] = W^T * X^T + bias ; 4 shared B-frags, 8 MFMA
  auto layer = [&](const bf16x8(&wf)[2][4], const f32x4(&bias)[2], int rb,
                   f32x4& A0, f32x4& A1) {
    const char* base = lds + rb * 4352 + rdbyte;
    bf16x8 x0 = *(const bf16x8*)(base);
    bf16x8 x1 = *(const bf16x8*)(base + 64);
    bf16x8 x2 = *(const bf16x8*)(base + 128);
    bf16x8 x3 = *(const bf16x8*)(base + 192);
    A0 = bias[0]; A1 = bias[1];
    A0 = MFMA16(wf[0][0], x0, A0); A1 = MFMA16(wf[1][0], x0, A1);
    A0 = MFMA16(wf[0][1], x1, A0); A1 = MFMA16(wf[1][1], x1, A1);
    A0 = MFMA16(wf[0][2], x2, A0); A1 = MFMA16(wf[1][2], x2, A1);
    A0 = MFMA16(wf[0][3], x3, A0); A1 = MFMA16(wf[1][3], x3, A1);
  };

  // one MLP eval; input in buffer sp; result (incl. b3) -> kx
  auto run_f = [&](int sp) {
    f32x4 A0, A1;
    float h[8];
    layer(wf1, bv1, sp, A0, A1);
#pragma unroll
    for (int r = 0; r < 4; ++r) {  // ELU(v) = max(v, exp(min(v,0))-1)
      h[r]     = fmaxf(A0[r], __expf(fminf(A0[r], 0.f)) - 1.f);
      h[4 + r] = fmaxf(A1[r], __expf(fminf(A1[r], 0.f)) - 1.f);
    }
    stv(sp ^ 1, h);
    barrier_lgkm();
    layer(wf2, bv2, sp ^ 1, A0, A1);
#pragma unroll
    for (int r = 0; r < 4; ++r) {
      h[r] = fmaxf(A0[r], 0.f); h[4 + r] = fmaxf(A1[r], 0.f);  // ReLU
    }
    stv(sp, h);
    barrier_lgkm();
    layer(wf3, bv3, sp, A0, A1);
#pragma unroll
    for (int r = 0; r < 4; ++r) { kx[r] = A0[r]; kx[4 + r] = A1[r]; }
  };

  // ------------- main loop: 64 pieces x 4 unrolled sub-steps -------------
#pragma unroll 1
  for (int p = 0; p < 64; ++p) {
    const bool pre = p < 63;
    if (pre) coeff_load(p + 1);  // prefetch next piece into regs

#pragma unroll
    for (int sub = 0; sub < 4; ++sub) {
      const float s0 = 0.25f * (float)sub;  // compile-time

      // ---- stage 1: k1 = f(z)*dX(s0); input buf0 ----
      run_f(0);
      {
        float h[8];
#pragma unroll
        for (int e = 0; e < 8; ++e) {
          const float dx = c1v[e] + (c2b[e] + c3b[e] * s0) * s0;
          kx[e] *= dx; sacc[e] = kx[e];
          h[e] = zr[e] + 0.125f * kx[e];
        }
        stv(1, h);
      }
      barrier_lgkm();

      // ---- stage 2: k2 at s0+0.125; input buf1 ----
      run_f(1);
      {
        const float sb = s0 + 0.125f;
        float h[8];
#pragma unroll
        for (int e = 0; e < 8; ++e) {
          dxb[e] = c1v[e] + (c2b[e] + c3b[e] * sb) * sb;
          kx[e] *= dxb[e]; sacc[e] += 2.f * kx[e];
          h[e] = zr[e] + 0.125f * kx[e];
        }
        stv(0, h);
      }
      barrier_lgkm();

      // ---- stage 3: k3 at same s as k2 (dx reused); input buf0 ----
      run_f(0);
      {
        float h[8];
#pragma unroll
        for (int e = 0; e < 8; ++e) {
          kx[e] *= dxb[e]; sacc[e] += 2.f * kx[e];
          h[e] = zr[e] + 0.25f * kx[e];
        }
        stv(1, h);
      }
      barrier_lgkm();

      // ---- stage 4: k4 at t+dt; input buf1 ----
      run_f(1);
      if (sub == 3) {
        if (pre) {
#pragma unroll
          for (int e = 0; e < 8; ++e) kx[e] *= cf[e][1];  // next piece, s=0
        } else {
#pragma unroll
          for (int e = 0; e < 8; ++e) kx[e] *= (c1v[e] + c2b[e] + c3b[e]);  // s=1
        }
      } else {
        const float sc = s0 + 0.25f;
#pragma unroll
        for (int e = 0; e < 8; ++e)
          kx[e] *= c1v[e] + (c2b[e] + c3b[e] * sc) * sc;
      }
      {
        float h[8];
#pragma unroll
        for (int e = 0; e < 8; ++e) {
          sacc[e] += kx[e];
          zr[e] += (0.25f / 6.f) * sacc[e];
          h[e] = zr[e];
        }
        stv(0, h);  // next step's f-input -> buf0
      }
      barrier_lgkm();
    }
    if (pre) coeff_adopt();
  }

  // ------------- readout: out = zT @ Wr + br -------------
  // reuse LDS as fp32 [16][132] (8448 B <= 8704 B)
  {
    float* zf = (float*)lds;
    *(f32x4*)(zf + l15 * 132 + cb0 + 4 * q)      = f32x4{zr[0], zr[1], zr[2], zr[3]};
    *(f32x4*)(zf + l15 * 132 + cb0 + 16 + 4 * q) = f32x4{zr[4], zr[5], zr[6], zr[7]};
  }
  barrier_lgkm();
  if (tid < 160) {
    const int row = tid / 10, o = tid - row * 10;
    const float* zf = (const float*)lds;
    float acc = br[o];
#pragma unroll 4
    for (int ch = 0; ch < 128; ++ch)
      acc = fmaf(zf[row * 132 + ch], Wr[ch * 10 + o], acc);
    out[(size_t)(row0 + row) * 10 + o] = acc;
  }
}

extern "C" void kernel_launch(void* const* d_in, const int* in_sizes, int n_in,
                              void* d_out, int out_size, void* d_ws, size_t ws_size,
                              hipStream_t stream) {
  const float* z0     = (const float*)d_in[0];
  const float* coeffs = (const float*)d_in[1];
  const float* W1 = (const float*)d_in[2]; const float* b1 = (const float*)d_in[3];
  const float* W2 = (const float*)d_in[4]; const float* b2 = (const float*)d_in[5];
  const float* W3 = (const float*)d_in[6]; const float* b3 = (const float*)d_in[7];
  const float* Wr = (const float*)d_in[8]; const float* br = (const float*)d_in[9];
  hipLaunchKernelGGL(cde_fused, dim3(256), dim3(256), 0, stream,
                     z0, coeffs, W1, b1, W2, b2, W3, b3, Wr, br, (float*)d_out);
}